// Round 13
// baseline (599.944 us; speedup 1.0000x reference)
//
#include <hip/hip_runtime.h>
#include <stdint.h>

// Problem constants (from reference): T=128, K=8, H=2048, E=64, I=768
constexpr int Tn = 128;
constexpr int Kn = 8;
constexpr int Hn = 2048;
constexpr int En = 64;
constexpr int In = 768;
constexpr int NP = Tn * Kn;      // 1024 pairs
constexpr int CT = 3;            // 256-col tiles (gateup)
constexpr int GDS = 8;           // d-slabs (gateup)
constexpr int GDSL = Hn / GDS;   // 256 d per slab
constexpr int NRG = 4;           // rowgroups of 8 (covers 32 rows/pass)

// ---------------- routing: build CSR of pair-ids per expert ----------------
__global__ void route_kernel(const int* __restrict__ idx32,
                             int* __restrict__ offsets,   // E+1 ints (512 B slot)
                             int* __restrict__ entries) { // NP pair ids
  __shared__ int s_cnt[En];
  __shared__ int s_cur[En];
  __shared__ int s_odd_or;
  const int tid = threadIdx.x;
  if (tid == 0) s_odd_or = 0;
  if (tid < En) s_cnt[tid] = 0;
  __syncthreads();
  if (tid < NP / 2) {
    if (idx32[2 * tid + 1] != 0) atomicOr(&s_odd_or, 1);
  }
  __syncthreads();
  const bool is64 = (s_odd_or == 0);
  const int e = is64 ? idx32[2 * tid] : idx32[tid];
  atomicAdd(&s_cnt[e], 1);
  __syncthreads();
  if (tid == 0) {
    int acc = 0;
    for (int i = 0; i < En; ++i) { s_cur[i] = acc; offsets[i] = acc; acc += s_cnt[i]; }
    offsets[En] = acc;
  }
  __syncthreads();
  const int pos = atomicAdd(&s_cur[e], 1);
  entries[pos] = tid;  // pair id = t*K + k
}

// ------- phase A: barrier-free 1-wave blocks, scalar-h × vector-w ---------
// grid = 2 * E * CT * GDS * NRG = 12288 blocks of 64 threads.
// Each wave: (m, e, 256-col tile, 256-d slab, 8-row group). No LDS, no syncs.
// h loads are wave-uniform (readfirstlane'd token) -> scalar operand of FMA.
// gu layout [2][NP][In] fp32, CSR-position-indexed, zeroed before launch.
__global__ __launch_bounds__(64, 8) void gateup_scalar(
    const float* __restrict__ hs, const float* __restrict__ wg,
    const float* __restrict__ wu, const int* __restrict__ offsets,
    const int* __restrict__ entries, float* __restrict__ gu) {
  const int b = blockIdx.x;
  const int rg0 = b & (NRG - 1);
  const int ds = (b >> 2) & (GDS - 1);
  const int tile = (b >> 5) % CT;
  const int em = (b >> 5) / CT;      // 0..127
  const int e = em & 63;
  const int m = em >> 6;             // 0 = gate, 1 = up
  const int beg = offsets[e];
  const int cnt = offsets[e + 1] - beg;
  if (cnt == 0 || rg0 * 8 >= cnt) return;

  const int lane = threadIdx.x;      // 0..63
  const int col = tile * 256 + lane * 4;
  const int dbeg = ds * GDSL;

  const float* W = m ? wu : wg;
  const float* wp = W + ((size_t)e * Hn + dbeg) * In + col;
  float* gup = gu + (size_t)m * NP * In;

  for (int r0 = rg0 * 8; r0 < cnt; r0 += NRG * 8) {
    // 8 wave-uniform token bases (scalar)
    const float* hr[8];
#pragma unroll
    for (int j = 0; j < 8; ++j) {
      const int p = entries[beg + r0 + min(j, cnt - 1 - r0)];  // uniform addr
      const int tk = __builtin_amdgcn_readfirstlane(p >> 3);   // force SGPR
      hr[j] = hs + (size_t)tk * Hn + dbeg;
    }

    float4 acc[8];
#pragma unroll
    for (int j = 0; j < 8; ++j) acc[j] = make_float4(0.f, 0.f, 0.f, 0.f);

    for (int dg = 0; dg < GDSL; dg += 8) {  // 32 iterations, no barriers
      float4 wv[8];
#pragma unroll
      for (int q = 0; q < 8; ++q)
        wv[q] = *reinterpret_cast<const float4*>(wp + (size_t)(dg + q) * In);
      float4 h0[8], h1[8];
#pragma unroll
      for (int j = 0; j < 8; ++j) {  // wave-uniform -> s_load_dwordx4
        h0[j] = *reinterpret_cast<const float4*>(hr[j] + dg);
        h1[j] = *reinterpret_cast<const float4*>(hr[j] + dg + 4);
      }
#pragma unroll
      for (int q = 0; q < 8; ++q) {
#pragma unroll
        for (int j = 0; j < 8; ++j) {
          const float4 hv4 = (q < 4) ? h0[j] : h1[j];
          const float h =
              (q & 3) == 0 ? hv4.x : (q & 3) == 1 ? hv4.y : (q & 3) == 2 ? hv4.z : hv4.w;
          acc[j].x = fmaf(h, wv[q].x, acc[j].x);
          acc[j].y = fmaf(h, wv[q].y, acc[j].y);
          acc[j].z = fmaf(h, wv[q].z, acc[j].z);
          acc[j].w = fmaf(h, wv[q].w, acc[j].w);
        }
      }
    }

#pragma unroll
    for (int j = 0; j < 8; ++j) {
      if (r0 + j < cnt) {
        const size_t ap = (size_t)(beg + r0 + j) * In + col;
        atomicAdd(&gup[ap], acc[j].x);
        atomicAdd(&gup[ap + 1], acc[j].y);
        atomicAdd(&gup[ap + 2], acc[j].z);
        atomicAdd(&gup[ap + 3], acc[j].w);
      }
    }
  }
}

// ------------- silu combine: act = silu(gate)*up, in place over gate -------
__global__ void silu_kernel(float* __restrict__ gu) {
  const int i = blockIdx.x * blockDim.x + threadIdx.x;  // over NP*In/4 float4
  float4* g4 = reinterpret_cast<float4*>(gu);
  const float4* u4 = reinterpret_cast<const float4*>(gu + (size_t)NP * In);
  float4 g = g4[i];
  const float4 u = u4[i];
  g.x = g.x / (1.f + __expf(-g.x)) * u.x;
  g.y = g.y / (1.f + __expf(-g.y)) * u.y;
  g.z = g.z / (1.f + __expf(-g.z)) * u.z;
  g.w = g.w / (1.f + __expf(-g.w)) * u.w;
  g4[i] = g;
}

// ---------------- phase B: out[t] += w * act @ Wd (proven R5 form) ---------
// grid = E * (H/128) = 1024; block 256.
__global__ __launch_bounds__(256, 2) void down_kernel(
    const float* __restrict__ act, const float* __restrict__ wd,
    const float* __restrict__ tkw, const int* __restrict__ offsets,
    const int* __restrict__ entries, float* __restrict__ out) {
  const int e = blockIdx.x >> 4;     // H/128 = 16 tiles
  const int tile = blockIdx.x & 15;
  const int beg = offsets[e];
  const int cnt = offsets[e + 1] - beg;
  if (cnt == 0) return;

  const int wave = threadIdx.x >> 6;
  const int lane = threadIdx.x & 63;
  const int col = tile * 128 + lane * 2;

  __shared__ float s_a[32][64];
  __shared__ int s_tok[32];
  __shared__ int s_arow[32];
  __shared__ float s_w[32];

  const float* wdp = wd + (size_t)e * In * Hn + col;

  for (int chunk = 0; chunk < cnt; chunk += 32) {
    __syncthreads();
    if (threadIdx.x < 32) {
      const int r = threadIdx.x;
      const int rr = min(r, cnt - chunk - 1);
      const int p = entries[beg + chunk + rr];
      s_tok[r] = p >> 3;
      s_w[r] = tkw[p];
      s_arow[r] = beg + chunk + rr;  // CSR position
    }
    __syncthreads();

    float2 acc[8];
#pragma unroll
    for (int j = 0; j < 8; ++j) acc[j] = make_float2(0.f, 0.f);

    for (int i0 = 0; i0 < In; i0 += 64) {
      {
        const int r = threadIdx.x >> 3;
        const int g = (threadIdx.x & 7) * 8;
        const float* src = act + (size_t)s_arow[r] * In + i0 + g;
        const float4 a = *reinterpret_cast<const float4*>(src);
        const float4 b4 = *reinterpret_cast<const float4*>(src + 4);
        *reinterpret_cast<float4*>(&s_a[r][g]) = a;
        *reinterpret_cast<float4*>(&s_a[r][g + 4]) = b4;
      }
      __syncthreads();
      const float* wdi = wdp + (size_t)i0 * Hn;
#pragma unroll 2
      for (int ig = 0; ig < 64; ig += 4) {
        float2 wdv[4];
#pragma unroll
        for (int q = 0; q < 4; ++q)
          wdv[q] = *reinterpret_cast<const float2*>(wdi + (size_t)(ig + q) * Hn);
#pragma unroll
        for (int j = 0; j < 8; ++j) {
          const float4 av = *reinterpret_cast<const float4*>(&s_a[wave * 8 + j][ig]);
          const float avv[4] = {av.x, av.y, av.z, av.w};
#pragma unroll
          for (int q = 0; q < 4; ++q) {
            acc[j].x = fmaf(avv[q], wdv[q].x, acc[j].x);
            acc[j].y = fmaf(avv[q], wdv[q].y, acc[j].y);
          }
        }
      }
      __syncthreads();
    }

#pragma unroll
    for (int j = 0; j < 8; ++j) {
      const int r = wave * 8 + j;
      if (chunk + r < cnt) {
        const float w = s_w[r];
        float* op = out + (size_t)s_tok[r] * Hn + col;
        atomicAdd(op, w * acc[j].x);
        atomicAdd(op + 1, w * acc[j].y);
      }
    }
  }
}

extern "C" void kernel_launch(void* const* d_in, const int* in_sizes, int n_in,
                              void* d_out, int out_size, void* d_ws, size_t ws_size,
                              hipStream_t stream) {
  const float* hs  = (const float*)d_in[0];
  const int*   idx = (const int*)d_in[1];
  const float* tkw = (const float*)d_in[2];
  const float* wg  = (const float*)d_in[3];
  const float* wu  = (const float*)d_in[4];
  const float* wd  = (const float*)d_in[5];
  float* out = (float*)d_out;

  // Workspace: [0,512) offsets | [512,4608) entries | [8192,..) gu[2][NP][In]
  char* ws = (char*)d_ws;
  int* offsets = (int*)ws;
  int* entries = (int*)(ws + 512);
  float* gu    = (float*)(ws + 8192);
  const size_t gu_bytes = (size_t)2 * NP * In * sizeof(float);

  route_kernel<<<1, NP, 0, stream>>>(idx, offsets, entries);
  hipMemsetAsync(d_out, 0, (size_t)Tn * Hn * sizeof(float), stream);
  hipMemsetAsync(gu, 0, gu_bytes, stream);
  gateup_scalar<<<2 * En * CT * GDS * NRG, 64, 0, stream>>>(hs, wg, wu, offsets,
                                                            entries, gu);
  silu_kernel<<<NP * In / 4 / 256, 256, 0, stream>>>(gu);
  down_kernel<<<En * (Hn / 128), 256, 0, stream>>>(gu, wd, tkw, offsets, entries, out);
}

// Round 14
// 590.520 us; speedup vs baseline: 1.0160x; 1.0160x over previous
//
#include <hip/hip_runtime.h>
#include <stdint.h>

// Problem constants (from reference): T=128, K=8, H=2048, E=64, I=768
constexpr int Tn = 128;
constexpr int Kn = 8;
constexpr int Hn = 2048;
constexpr int En = 64;
constexpr int In = 768;
constexpr int NP = Tn * Kn;      // 1024 pairs
constexpr int CT = 3;            // 256-col tiles (gateup)
constexpr int GDS = 8;           // d-slabs (gateup)
constexpr int GDSL = Hn / GDS;   // 256 d per slab

// ---------------- routing: build CSR of pair-ids per expert ----------------
__global__ void route_kernel(const int* __restrict__ idx32,
                             int* __restrict__ offsets,   // E+1 ints (512 B slot)
                             int* __restrict__ entries) { // NP pair ids
  __shared__ int s_cnt[En];
  __shared__ int s_cur[En];
  __shared__ int s_odd_or;
  const int tid = threadIdx.x;
  if (tid == 0) s_odd_or = 0;
  if (tid < En) s_cnt[tid] = 0;
  __syncthreads();
  if (tid < NP / 2) {
    if (idx32[2 * tid + 1] != 0) atomicOr(&s_odd_or, 1);
  }
  __syncthreads();
  const bool is64 = (s_odd_or == 0);
  const int e = is64 ? idx32[2 * tid] : idx32[tid];
  atomicAdd(&s_cnt[e], 1);
  __syncthreads();
  if (tid == 0) {
    int acc = 0;
    for (int i = 0; i < En; ++i) { s_cur[i] = acc; offsets[i] = acc; acc += s_cnt[i]; }
    offsets[En] = acc;
  }
  __syncthreads();
  const int pos = atomicAdd(&s_cur[e], 1);
  entries[pos] = tid;  // pair id = t*K + k
}

// ------- gateup deep body: 16x dwordx4 bursts, zero barriers in hot loop ---
template <int RPW>
__device__ __forceinline__ void gud_body(
    const float* __restrict__ wp, const float (*__restrict__ s_h)[257],
    int wave, int cntc, size_t ap0, float* __restrict__ gup) {
  float4 acc[RPW];
#pragma unroll
  for (int j = 0; j < RPW; ++j) acc[j] = make_float4(0.f, 0.f, 0.f, 0.f);
  const int r0 = wave * RPW;

  for (int dg = 0; dg < GDSL; dg += 16) {  // 16 iters/slab, NO barriers
    float4 wv[16];                          // 16 KB in flight per wave
#pragma unroll
    for (int q = 0; q < 16; ++q)
      wv[q] = *reinterpret_cast<const float4*>(wp + (size_t)(dg + q) * In);
#pragma unroll
    for (int s = 0; s < 4; ++s) {
      float4 h4[RPW];  // lane-uniform LDS broadcast (free)
#pragma unroll
      for (int j = 0; j < RPW; ++j)
        h4[j] = *reinterpret_cast<const float4*>(&s_h[r0 + j][dg + s * 4]);
#pragma unroll
      for (int j = 0; j < RPW; ++j) {
        acc[j].x = fmaf(h4[j].x, wv[s * 4].x, acc[j].x);
        acc[j].y = fmaf(h4[j].x, wv[s * 4].y, acc[j].y);
        acc[j].z = fmaf(h4[j].x, wv[s * 4].z, acc[j].z);
        acc[j].w = fmaf(h4[j].x, wv[s * 4].w, acc[j].w);
        acc[j].x = fmaf(h4[j].y, wv[s * 4 + 1].x, acc[j].x);
        acc[j].y = fmaf(h4[j].y, wv[s * 4 + 1].y, acc[j].y);
        acc[j].z = fmaf(h4[j].y, wv[s * 4 + 1].z, acc[j].z);
        acc[j].w = fmaf(h4[j].y, wv[s * 4 + 1].w, acc[j].w);
        acc[j].x = fmaf(h4[j].z, wv[s * 4 + 2].x, acc[j].x);
        acc[j].y = fmaf(h4[j].z, wv[s * 4 + 2].y, acc[j].y);
        acc[j].z = fmaf(h4[j].z, wv[s * 4 + 2].z, acc[j].z);
        acc[j].w = fmaf(h4[j].z, wv[s * 4 + 2].w, acc[j].w);
        acc[j].x = fmaf(h4[j].w, wv[s * 4 + 3].x, acc[j].x);
        acc[j].y = fmaf(h4[j].w, wv[s * 4 + 3].y, acc[j].y);
        acc[j].z = fmaf(h4[j].w, wv[s * 4 + 3].z, acc[j].z);
        acc[j].w = fmaf(h4[j].w, wv[s * 4 + 3].w, acc[j].w);
      }
    }
  }

#pragma unroll
  for (int j = 0; j < RPW; ++j) {
    const int row = r0 + j;
    if (row < cntc) {
      const size_t ap = ap0 + (size_t)row * In;
      atomicAdd(&gup[ap], acc[j].x);
      atomicAdd(&gup[ap + 1], acc[j].y);
      atomicAdd(&gup[ap + 2], acc[j].z);
      atomicAdd(&gup[ap + 3], acc[j].w);
    }
  }
}

// ------- phase A: h staged once/chunk; barrier-free weight streaming -------
// grid = 2 * E * CT * GDS = 3072; block 256 = 4 waves.
// gu layout [2][NP][In] fp32 (CSR-position-indexed), zeroed before launch.
__global__ __launch_bounds__(256, 3) void gateup_deep(
    const float* __restrict__ hs, const float* __restrict__ wg,
    const float* __restrict__ wu, const int* __restrict__ offsets,
    const int* __restrict__ entries, float* __restrict__ gu) {
  const int b = blockIdx.x;
  const int ds = b & (GDS - 1);
  const int tile = (b >> 3) % CT;
  const int em = (b >> 3) / CT;      // 0..127
  const int e = em & 63;
  const int m = em >> 6;             // 0 = gate, 1 = up
  const int beg = offsets[e];
  const int cnt = offsets[e + 1] - beg;
  if (cnt == 0) return;

  const int t = threadIdx.x;
  const int wave = t >> 6;
  const int lane = t & 63;
  const int dbeg = ds * GDSL;
  const int col = tile * 256 + lane * 4;

  __shared__ float s_h[32][257];     // 32.9 KB; stride 257 -> staging 2-way max
  __shared__ int s_tok[32];

  const float* W = m ? wu : wg;
  const float* wp = W + ((size_t)e * Hn + dbeg) * In + col;
  float* gup = gu + (size_t)m * NP * In;

  for (int chunk = 0; chunk < cnt; chunk += 32) {
    const int cntc = min(cnt - chunk, 32);

    __syncthreads();  // prev chunk done with s_h/s_tok
    if (t < 32) s_tok[t] = entries[beg + chunk + min(t, cntc - 1)] >> 3;
    __syncthreads();
    {  // stage h[rows, dbeg:dbeg+256] once per chunk
      const int r = t & 31;            // row (banks spread across 32 rows)
      const int c0 = (t >> 5) * 32;    // 8 col-groups of 32
      const float* src = hs + (size_t)s_tok[r] * Hn + dbeg + c0;
#pragma unroll
      for (int q = 0; q < 8; ++q)
        *reinterpret_cast<float4*>(&s_h[r][c0 + q * 4]) =
            *reinterpret_cast<const float4*>(src + q * 4);
    }
    __syncthreads();

    const size_t ap0 = (size_t)(beg + chunk) * In + col;
    if (cntc <= 8)
      gud_body<2>(wp, s_h, wave, cntc, ap0, gup);
    else if (cntc <= 16)
      gud_body<4>(wp, s_h, wave, cntc, ap0, gup);
    else
      gud_body<8>(wp, s_h, wave, cntc, ap0, gup);
  }
}

// ------------- silu combine: act = silu(gate)*up, in place over gate -------
__global__ void silu_kernel(float* __restrict__ gu) {
  const int i = blockIdx.x * blockDim.x + threadIdx.x;  // over NP*In/4 float4
  float4* g4 = reinterpret_cast<float4*>(gu);
  const float4* u4 = reinterpret_cast<const float4*>(gu + (size_t)NP * In);
  float4 g = g4[i];
  const float4 u = u4[i];
  g.x = g.x / (1.f + __expf(-g.x)) * u.x;
  g.y = g.y / (1.f + __expf(-g.y)) * u.y;
  g.z = g.z / (1.f + __expf(-g.z)) * u.z;
  g.w = g.w / (1.f + __expf(-g.w)) * u.w;
  g4[i] = g;
}

// ---------------- phase B: out[t] += w * act @ Wd (proven R5 form) ---------
// grid = E * (H/128) = 1024; block 256.
__global__ __launch_bounds__(256, 2) void down_kernel(
    const float* __restrict__ act, const float* __restrict__ wd,
    const float* __restrict__ tkw, const int* __restrict__ offsets,
    const int* __restrict__ entries, float* __restrict__ out) {
  const int e = blockIdx.x >> 4;     // H/128 = 16 tiles
  const int tile = blockIdx.x & 15;
  const int beg = offsets[e];
  const int cnt = offsets[e + 1] - beg;
  if (cnt == 0) return;

  const int wave = threadIdx.x >> 6;
  const int lane = threadIdx.x & 63;
  const int col = tile * 128 + lane * 2;

  __shared__ float s_a[32][64];
  __shared__ int s_tok[32];
  __shared__ int s_arow[32];
  __shared__ float s_w[32];

  const float* wdp = wd + (size_t)e * In * Hn + col;

  for (int chunk = 0; chunk < cnt; chunk += 32) {
    __syncthreads();
    if (threadIdx.x < 32) {
      const int r = threadIdx.x;
      const int rr = min(r, cnt - chunk - 1);
      const int p = entries[beg + chunk + rr];
      s_tok[r] = p >> 3;
      s_w[r] = tkw[p];
      s_arow[r] = beg + chunk + rr;  // CSR position
    }
    __syncthreads();

    float2 acc[8];
#pragma unroll
    for (int j = 0; j < 8; ++j) acc[j] = make_float2(0.f, 0.f);

    for (int i0 = 0; i0 < In; i0 += 64) {
      {
        const int r = threadIdx.x >> 3;
        const int g = (threadIdx.x & 7) * 8;
        const float* src = act + (size_t)s_arow[r] * In + i0 + g;
        const float4 a = *reinterpret_cast<const float4*>(src);
        const float4 b4 = *reinterpret_cast<const float4*>(src + 4);
        *reinterpret_cast<float4*>(&s_a[r][g]) = a;
        *reinterpret_cast<float4*>(&s_a[r][g + 4]) = b4;
      }
      __syncthreads();
      const float* wdi = wdp + (size_t)i0 * Hn;
#pragma unroll 2
      for (int ig = 0; ig < 64; ig += 4) {
        float2 wdv[4];
#pragma unroll
        for (int q = 0; q < 4; ++q)
          wdv[q] = *reinterpret_cast<const float2*>(wdi + (size_t)(ig + q) * Hn);
#pragma unroll
        for (int j = 0; j < 8; ++j) {
          const float4 av = *reinterpret_cast<const float4*>(&s_a[wave * 8 + j][ig]);
          const float avv[4] = {av.x, av.y, av.z, av.w};
#pragma unroll
          for (int q = 0; q < 4; ++q) {
            acc[j].x = fmaf(avv[q], wdv[q].x, acc[j].x);
            acc[j].y = fmaf(avv[q], wdv[q].y, acc[j].y);
          }
        }
      }
      __syncthreads();
    }

#pragma unroll
    for (int j = 0; j < 8; ++j) {
      const int r = wave * 8 + j;
      if (chunk + r < cnt) {
        const float w = s_w[r];
        float* op = out + (size_t)s_tok[r] * Hn + col;
        atomicAdd(op, w * acc[j].x);
        atomicAdd(op + 1, w * acc[j].y);
      }
    }
  }
}

extern "C" void kernel_launch(void* const* d_in, const int* in_sizes, int n_in,
                              void* d_out, int out_size, void* d_ws, size_t ws_size,
                              hipStream_t stream) {
  const float* hs  = (const float*)d_in[0];
  const int*   idx = (const int*)d_in[1];
  const float* tkw = (const float*)d_in[2];
  const float* wg  = (const float*)d_in[3];
  const float* wu  = (const float*)d_in[4];
  const float* wd  = (const float*)d_in[5];
  float* out = (float*)d_out;

  // Workspace: [0,512) offsets | [512,4608) entries | [8192,..) gu[2][NP][In]
  char* ws = (char*)d_ws;
  int* offsets = (int*)ws;
  int* entries = (int*)(ws + 512);
  float* gu    = (float*)(ws + 8192);
  const size_t gu_bytes = (size_t)2 * NP * In * sizeof(float);

  route_kernel<<<1, NP, 0, stream>>>(idx, offsets, entries);
  hipMemsetAsync(d_out, 0, (size_t)Tn * Hn * sizeof(float), stream);
  hipMemsetAsync(gu, 0, gu_bytes, stream);
  gateup_deep<<<2 * En * CT * GDS, 256, 0, stream>>>(hs, wg, wu, offsets, entries, gu);
  silu_kernel<<<NP * In / 4 / 256, 256, 0, stream>>>(gu);
  down_kernel<<<En * (Hn / 128), 256, 0, stream>>>(gu, wd, tkw, offsets, entries, out);
}

// Round 15
// 515.105 us; speedup vs baseline: 1.1647x; 1.1464x over previous
//
#include <hip/hip_runtime.h>
#include <stdint.h>

// Problem constants (from reference): T=128, K=8, H=2048, E=64, I=768
constexpr int Tn = 128;
constexpr int Kn = 8;
constexpr int Hn = 2048;
constexpr int En = 64;
constexpr int In = 768;
constexpr int NP = Tn * Kn;      // 1024 pairs
constexpr int NTI = In / 128;    // 6 col tiles of 128 (gateup)
constexpr int GDS = 8;           // d-slabs in gateup (256 d each)
constexpr int GDSL = Hn / GDS;   // 256
constexpr int DSB = 3;           // i-slabs in down (256 i each)
constexpr int ISL = In / DSB;    // 256

// ---------------- routing: build CSR of pair-ids per expert ----------------
__global__ void route_kernel(const int* __restrict__ idx32,
                             int* __restrict__ offsets,   // E+1 ints (512 B slot)
                             int* __restrict__ entries) { // NP pair ids
  __shared__ int s_cnt[En];
  __shared__ int s_cur[En];
  __shared__ int s_odd_or;
  const int tid = threadIdx.x;
  if (tid == 0) s_odd_or = 0;
  if (tid < En) s_cnt[tid] = 0;
  __syncthreads();
  if (tid < NP / 2) {
    if (idx32[2 * tid + 1] != 0) atomicOr(&s_odd_or, 1);
  }
  __syncthreads();
  const bool is64 = (s_odd_or == 0);
  const int e = is64 ? idx32[2 * tid] : idx32[tid];
  atomicAdd(&s_cnt[e], 1);
  __syncthreads();
  if (tid == 0) {
    int acc = 0;
    for (int i = 0; i < En; ++i) { s_cur[i] = acc; offsets[i] = acc; acc += s_cnt[i]; }
    offsets[En] = acc;
  }
  __syncthreads();
  const int pos = atomicAdd(&s_cur[e], 1);
  entries[pos] = tid;  // pair id = t*K + k
}

// ------- phase A: R12 mono inner loop, 8-way d-split, 24 blocks/CU queued --
// grid = 2 * E * NTI * GDS = 6144; block 256 = 4 waves, 8 rows/wave.
// gu layout [2][NP][In] fp32 (CSR-position-indexed), zeroed before launch.
__global__ __launch_bounds__(256, 6) void gateup_occ(
    const float* __restrict__ hs, const float* __restrict__ wg,
    const float* __restrict__ wu, const int* __restrict__ offsets,
    const int* __restrict__ entries, float* __restrict__ gu) {
  const int b = blockIdx.x;
  const int ds = b & (GDS - 1);
  const int tile = (b >> 3) % NTI;
  const int em = (b >> 3) / NTI;     // 0..127
  const int e = em & 63;
  const int m = em >> 6;             // 0 = gate, 1 = up
  const int beg = offsets[e];
  const int cnt = offsets[e + 1] - beg;
  if (cnt == 0) return;

  const int wave = threadIdx.x >> 6;
  const int lane = threadIdx.x & 63;
  const int dbeg = ds * GDSL;
  const int col = tile * 128 + lane * 2;

  __shared__ float s_h[32][64];
  __shared__ int s_tok[32];

  const float* W = m ? wu : wg;
  const float* wp = W + (size_t)e * Hn * In + col;
  float* gup = gu + (size_t)m * NP * In;

  for (int chunk = 0; chunk < cnt; chunk += 32) {
    __syncthreads();
    if (threadIdx.x < 32) {
      const int r = threadIdx.x;
      s_tok[r] = entries[beg + chunk + min(r, cnt - chunk - 1)] >> 3;  // clamp
    }
    __syncthreads();

    float2 acc[8];
#pragma unroll
    for (int j = 0; j < 8; ++j) acc[j] = make_float2(0.f, 0.f);

    for (int d0 = dbeg; d0 < dbeg + GDSL; d0 += 64) {
      {  // stage h[rows, d0:d0+64] -> LDS (32 rows x 64 floats)
        const int r = threadIdx.x >> 3;
        const int g = (threadIdx.x & 7) * 8;
        const float* src = hs + (size_t)s_tok[r] * Hn + d0 + g;
        const float4 a = *reinterpret_cast<const float4*>(src);
        const float4 b4 = *reinterpret_cast<const float4*>(src + 4);
        *reinterpret_cast<float4*>(&s_h[r][g]) = a;
        *reinterpret_cast<float4*>(&s_h[r][g + 4]) = b4;
      }
      __syncthreads();
      const float* wdd = wp + (size_t)d0 * In;
#pragma unroll 2
      for (int dg = 0; dg < 64; dg += 4) {
        float2 wv[4];
#pragma unroll
        for (int q = 0; q < 4; ++q)
          wv[q] = *reinterpret_cast<const float2*>(wdd + (size_t)(dg + q) * In);
#pragma unroll
        for (int j = 0; j < 8; ++j) {
          const float4 hv = *reinterpret_cast<const float4*>(&s_h[wave * 8 + j][dg]);
          const float hvv[4] = {hv.x, hv.y, hv.z, hv.w};
#pragma unroll
          for (int q = 0; q < 4; ++q) {
            acc[j].x = fmaf(hvv[q], wv[q].x, acc[j].x);
            acc[j].y = fmaf(hvv[q], wv[q].y, acc[j].y);
          }
        }
      }
      __syncthreads();
    }

#pragma unroll
    for (int j = 0; j < 8; ++j) {
      const int r = wave * 8 + j;
      if (chunk + r < cnt) {
        const size_t ap = (size_t)(beg + chunk + r) * In + col;
        atomicAdd(&gup[ap], acc[j].x);
        atomicAdd(&gup[ap + 1], acc[j].y);
      }
    }
  }
}

// ------------- silu combine: act = silu(gate)*up, in place over gate -------
__global__ void silu_kernel(float* __restrict__ gu) {
  const int i = blockIdx.x * blockDim.x + threadIdx.x;  // over NP*In/4 float4
  float4* g4 = reinterpret_cast<float4*>(gu);
  const float4* u4 = reinterpret_cast<const float4*>(gu + (size_t)NP * In);
  float4 g = g4[i];
  const float4 u = u4[i];
  g.x = g.x / (1.f + __expf(-g.x)) * u.x;
  g.y = g.y / (1.f + __expf(-g.y)) * u.y;
  g.z = g.z / (1.f + __expf(-g.z)) * u.z;
  g.w = g.w / (1.f + __expf(-g.w)) * u.w;
  g4[i] = g;
}

// ---------------- phase B: out[t] += w * act @ Wd, 3-way i-split ----------
// grid = E * 16 * DSB = 3072; block 256.
__global__ __launch_bounds__(256, 6) void down_occ(
    const float* __restrict__ act, const float* __restrict__ wd,
    const float* __restrict__ tkw, const int* __restrict__ offsets,
    const int* __restrict__ entries, float* __restrict__ out) {
  const int b = blockIdx.x;
  const int isl = b % DSB;
  const int tile = (b / DSB) & 15;   // H/128 = 16 tiles
  const int e = b / (DSB * 16);
  const int beg = offsets[e];
  const int cnt = offsets[e + 1] - beg;
  if (cnt == 0) return;

  const int wave = threadIdx.x >> 6;
  const int lane = threadIdx.x & 63;
  const int col = tile * 128 + lane * 2;
  const int ibeg = isl * ISL;

  __shared__ float s_a[32][64];
  __shared__ int s_tok[32];
  __shared__ int s_arow[32];
  __shared__ float s_w[32];

  const float* wdp = wd + (size_t)e * In * Hn + col;

  for (int chunk = 0; chunk < cnt; chunk += 32) {
    __syncthreads();
    if (threadIdx.x < 32) {
      const int r = threadIdx.x;
      const int rr = min(r, cnt - chunk - 1);
      const int p = entries[beg + chunk + rr];
      s_tok[r] = p >> 3;
      s_w[r] = tkw[p];
      s_arow[r] = beg + chunk + rr;  // CSR position
    }
    __syncthreads();

    float2 acc[8];
#pragma unroll
    for (int j = 0; j < 8; ++j) acc[j] = make_float2(0.f, 0.f);

    for (int i0 = ibeg; i0 < ibeg + ISL; i0 += 64) {
      {
        const int r = threadIdx.x >> 3;
        const int g = (threadIdx.x & 7) * 8;
        const float* src = act + (size_t)s_arow[r] * In + i0 + g;
        const float4 a = *reinterpret_cast<const float4*>(src);
        const float4 b4 = *reinterpret_cast<const float4*>(src + 4);
        *reinterpret_cast<float4*>(&s_a[r][g]) = a;
        *reinterpret_cast<float4*>(&s_a[r][g + 4]) = b4;
      }
      __syncthreads();
      const float* wdi = wdp + (size_t)i0 * Hn;
#pragma unroll 2
      for (int ig = 0; ig < 64; ig += 4) {
        float2 wdv[4];
#pragma unroll
        for (int q = 0; q < 4; ++q)
          wdv[q] = *reinterpret_cast<const float2*>(wdi + (size_t)(ig + q) * Hn);
#pragma unroll
        for (int j = 0; j < 8; ++j) {
          const float4 av = *reinterpret_cast<const float4*>(&s_a[wave * 8 + j][ig]);
          const float avv[4] = {av.x, av.y, av.z, av.w};
#pragma unroll
          for (int q = 0; q < 4; ++q) {
            acc[j].x = fmaf(avv[q], wdv[q].x, acc[j].x);
            acc[j].y = fmaf(avv[q], wdv[q].y, acc[j].y);
          }
        }
      }
      __syncthreads();
    }

#pragma unroll
    for (int j = 0; j < 8; ++j) {
      const int r = wave * 8 + j;
      if (chunk + r < cnt) {
        const float w = s_w[r];
        float* op = out + (size_t)s_tok[r] * Hn + col;
        atomicAdd(op, w * acc[j].x);
        atomicAdd(op + 1, w * acc[j].y);
      }
    }
  }
}

extern "C" void kernel_launch(void* const* d_in, const int* in_sizes, int n_in,
                              void* d_out, int out_size, void* d_ws, size_t ws_size,
                              hipStream_t stream) {
  const float* hs  = (const float*)d_in[0];
  const int*   idx = (const int*)d_in[1];
  const float* tkw = (const float*)d_in[2];
  const float* wg  = (const float*)d_in[3];
  const float* wu  = (const float*)d_in[4];
  const float* wd  = (const float*)d_in[5];
  float* out = (float*)d_out;

  // Workspace: [0,512) offsets | [512,4608) entries | [8192,..) gu[2][NP][In]
  char* ws = (char*)d_ws;
  int* offsets = (int*)ws;
  int* entries = (int*)(ws + 512);
  float* gu    = (float*)(ws + 8192);
  const size_t gu_bytes = (size_t)2 * NP * In * sizeof(float);

  route_kernel<<<1, NP, 0, stream>>>(idx, offsets, entries);
  hipMemsetAsync(d_out, 0, (size_t)Tn * Hn * sizeof(float), stream);
  hipMemsetAsync(gu, 0, gu_bytes, stream);
  gateup_occ<<<2 * En * NTI * GDS, 256, 0, stream>>>(hs, wg, wu, offsets, entries, gu);
  silu_kernel<<<NP * In / 4 / 256, 256, 0, stream>>>(gu);
  down_occ<<<En * 16 * DSB, 256, 0, stream>>>(gu, wd, tkw, offsets, entries, out);
}